// Round 2
// baseline (727.069 us; speedup 1.0000x reference)
//
#include <hip/hip_runtime.h>
#include <math.h>

#define CIN  16
#define COUT 64
#define H    256
#define W    256
#define OH   254
#define OW   254

// Pre-transpose weights from [cout][cin][3][3] to [cin*9 + kh*3 + kw][cout]
// so the hot loop's weight reads are contiguous wave-uniform scalar loads.
__global__ void wtrans_kernel(const float* __restrict__ w, float* __restrict__ wt) {
    int idx = blockIdx.x * blockDim.x + threadIdx.x;
    if (idx < CIN * 9 * COUT) {
        int co = idx % COUT;
        int k  = idx / COUT;          // cin*9 + kh*3 + kw
        int cin = k / 9, r = k % 9;
        wt[idx] = w[(co * CIN + cin) * 9 + r];
    }
}

// One thread per output pixel. acc[64] in VGPRs, weights via SGPR (uniform),
// fused min over cout + tanh(tanh()).
__global__ __launch_bounds__(256) void conv_min_tanh_kernel(
        const float* __restrict__ x, const float* __restrict__ wt,
        const float* __restrict__ bias, float* __restrict__ out) {
    const int ow  = threadIdx.x;                  // 0..255 (254 active)
    const int owc = ow < OW ? ow : OW - 1;        // clamp inactive lanes in-bounds
    const int oh  = blockIdx.x % OH;
    const int b   = blockIdx.x / OH;

    float acc[COUT];
#pragma unroll
    for (int co = 0; co < COUT; ++co) acc[co] = bias[co];

    const float* xb = x + ((size_t)b * CIN) * (H * W) + oh * W + owc;

    for (int cin = 0; cin < CIN; ++cin) {
        const float* xc = xb + cin * (H * W);
#pragma unroll
        for (int kh = 0; kh < 3; ++kh) {
            const float* xr = xc + kh * W;
            float x0 = xr[0];
            float x1 = xr[1];
            float x2 = xr[2];
            const float* wp = wt + ((cin * 3 + kh) * 3) * COUT;
#pragma unroll
            for (int co = 0; co < COUT; ++co) acc[co] = fmaf(x0, wp[co], acc[co]);
#pragma unroll
            for (int co = 0; co < COUT; ++co) acc[co] = fmaf(x1, wp[COUT + co], acc[co]);
#pragma unroll
            for (int co = 0; co < COUT; ++co) acc[co] = fmaf(x2, wp[2 * COUT + co], acc[co]);
        }
    }

    float m = acc[0];
#pragma unroll
    for (int co = 1; co < COUT; ++co) m = fminf(m, acc[co]);
    m = tanhf(tanhf(m));

    if (ow < OW) out[((size_t)b * OH + oh) * OW + ow] = m;
}

extern "C" void kernel_launch(void* const* d_in, const int* in_sizes, int n_in,
                              void* d_out, int out_size, void* d_ws, size_t ws_size,
                              hipStream_t stream) {
    const float* x    = (const float*)d_in[0];
    const float* w    = (const float*)d_in[1];
    const float* bias = (const float*)d_in[2];
    float* out = (float*)d_out;
    float* wt  = (float*)d_ws;   // 144*64*4 = 36,864 bytes of scratch

    wtrans_kernel<<<(CIN * 9 * COUT + 255) / 256, 256, 0, stream>>>(w, wt);
    conv_min_tanh_kernel<<<64 * OH, 256, 0, stream>>>(x, wt, bias, out);
}

// Round 3
// 166.396 us; speedup vs baseline: 4.3695x; 4.3695x over previous
//
#include <hip/hip_runtime.h>
#include <math.h>

#define CIN   16
#define COUT  64
#define H     256
#define W     256
#define OH    254
#define OW    254
#define NTAP  9

typedef _Float16 f16x8 __attribute__((ext_vector_type(8)));
typedef float    f32x16 __attribute__((ext_vector_type(16)));

// ---------------------------------------------------------------------------
// Pre-kernel: pack weights into MFMA A-fragment order, fp16 hi/lo split.
// wpk flat layout: [split 2][tap 9][msub 2][lane 64][e 8]
//   co  = (lane&31) + 32*msub
//   cin = 8*(lane>>5) + e          <-- our k-slot semantic (mirrored on B side)
//   tap = kh*3 + kw
// ---------------------------------------------------------------------------
__global__ void wpack_kernel(const float* __restrict__ w, _Float16* __restrict__ wpk) {
    int idx = blockIdx.x * 256 + threadIdx.x;     // 0 .. 18431
    if (idx >= 2 * NTAP * 2 * 64 * 8) return;
    int e = idx & 7;
    int l = (idx >> 3) & 63;
    int m = (idx >> 9) & 1;
    int q = idx >> 10;            // s*9 + t
    int t = q % NTAP;
    int s = q / NTAP;
    int co  = (l & 31) + 32 * m;
    int cin = 8 * (l >> 5) + e;
    int kh = t / 3, kw = t % 3;
    float wv = w[((co * CIN + cin) * 3 + kh) * 3 + kw];
    _Float16 hi = (_Float16)wv;
    float lo = wv - (float)hi;
    wpk[idx] = (s == 0) ? hi : (_Float16)lo;
}

// ---------------------------------------------------------------------------
// Main kernel: block = 256 threads = 4 waves, covers 2 output rows x 256 px.
// wave w: row = oh0 + (w>>1), px base = (w&1)*128; each wave = 64co x 128px.
// Per tap: A = weight frags (2 msub x hi/lo), B = x frag from swizzled LDS.
// ---------------------------------------------------------------------------
__global__ __launch_bounds__(256, 2) void conv_mfma_kernel(
        const float* __restrict__ x, const f16x8* __restrict__ wpk,
        const float* __restrict__ bias, float* __restrict__ out) {
    // xs: [4 h][256 w][2 g] slots of 8 fp16 (cin half g: cin 8g..8g+7), XOR-swizzled
    __shared__ f16x8 xsv[4 * 512];          // 32 KiB
    __shared__ f16x8 wv[2 * NTAP * 2 * 64]; // 36 KiB
    const int tid = threadIdx.x;

    // XCD-aware bijective swizzle: grid = 64*127 = 8128 = 8*1016
    int bid = blockIdx.x;
    int nb  = (bid & 7) * 1016 + (bid >> 3);
    int b   = nb / 127;
    int ohb = nb - b * 127;
    int oh0 = ohb * 2;                      // output rows oh0, oh0+1 (<=252)

    // ---- stage x: 16cin x 4h x 256w fp32 -> fp16 LDS ----
    const float* xb = x + (size_t)b * CIN * H * W;
    for (int it = 0; it < 8; ++it) {        // all 256 threads share (h,g); w = tid
        int h = it & 3;
        int g = it >> 2;
        float v[8];
#pragma unroll
        for (int c = 0; c < 8; ++c)
            v[c] = xb[(size_t)(8 * g + c) * (H * W) + (oh0 + h) * W + tid];
        f16x8 p;
#pragma unroll
        for (int c = 0; c < 8; ++c) p[c] = (_Float16)v[c];
        int slot = h * 512 + (((tid << 1) | g) ^ ((tid >> 2) & 1));
        xsv[slot] = p;
    }
    // ---- stage weights (linear copy) ----
    for (int i = 0; i < NTAP; ++i) wv[i * 256 + tid] = wpk[i * 256 + tid];
    __syncthreads();

    const int lane = tid & 63;
    const int wave = tid >> 6;
    const int ohl  = wave >> 1;             // local output row 0/1
    const int ph   = (wave & 1) * 128;      // pixel base 0/128
    const int l31  = lane & 31;
    const int g2   = lane >> 5;             // k-slot group (cin half)

    // bias init per C/D layout: col=lane&31(px), row=(r&3)+8*(r>>2)+4*(lane>>5)+32m (co)
    f32x16 binit[2];
#pragma unroll
    for (int m = 0; m < 2; ++m)
#pragma unroll
        for (int r = 0; r < 16; ++r)
            binit[m][r] = bias[(r & 3) + 8 * (r >> 2) + 4 * g2 + 32 * m];

    f32x16 acc[2][4];
#pragma unroll
    for (int m = 0; m < 2; ++m)
#pragma unroll
        for (int n = 0; n < 4; ++n) acc[m][n] = binit[m];

#pragma unroll
    for (int t = 0; t < NTAP; ++t) {
        const int kh = t / 3, kw = t % 3;
        f16x8 ahi0 = wv[((0 * NTAP + t) * 2 + 0) * 64 + lane];
        f16x8 ahi1 = wv[((0 * NTAP + t) * 2 + 1) * 64 + lane];
        f16x8 alo0 = wv[((1 * NTAP + t) * 2 + 0) * 64 + lane];
        f16x8 alo1 = wv[((1 * NTAP + t) * 2 + 1) * 64 + lane];
        const int h = ohl + kh;
#pragma unroll
        for (int n = 0; n < 4; ++n) {
            int w = ph + 32 * n + l31 + kw;      // up to 257 for pad pixels
            if (w > 255) w = 255;                // clamp (outputs never stored)
            int slot = h * 512 + (((w << 1) | g2) ^ ((w >> 2) & 1));
            f16x8 bf = xsv[slot];
            acc[0][n] = __builtin_amdgcn_mfma_f32_32x32x16_f16(ahi0, bf, acc[0][n], 0, 0, 0);
            acc[1][n] = __builtin_amdgcn_mfma_f32_32x32x16_f16(ahi1, bf, acc[1][n], 0, 0, 0);
            acc[0][n] = __builtin_amdgcn_mfma_f32_32x32x16_f16(alo0, bf, acc[0][n], 0, 0, 0);
            acc[1][n] = __builtin_amdgcn_mfma_f32_32x32x16_f16(alo1, bf, acc[1][n], 0, 0, 0);
        }
    }

    // ---- epilogue: min over cout, tanh(tanh()), store ----
    const int oh = oh0 + ohl;
#pragma unroll
    for (int n = 0; n < 4; ++n) {
        float mn = fminf(acc[0][n][0], acc[1][n][0]);
#pragma unroll
        for (int r = 1; r < 16; ++r)
            mn = fminf(mn, fminf(acc[0][n][r], acc[1][n][r]));
        mn = fminf(mn, __shfl_xor(mn, 32));   // fold the two co lane-halves
        float t2 = tanhf(tanhf(mn));
        int px = ph + 32 * n + l31;
        if (g2 == 0 && px < OW)
            out[((size_t)b * OH + oh) * OW + px] = t2;
    }
}

extern "C" void kernel_launch(void* const* d_in, const int* in_sizes, int n_in,
                              void* d_out, int out_size, void* d_ws, size_t ws_size,
                              hipStream_t stream) {
    const float* x    = (const float*)d_in[0];
    const float* w    = (const float*)d_in[1];
    const float* bias = (const float*)d_in[2];
    float* out = (float*)d_out;
    _Float16* wpk = (_Float16*)d_ws;   // 18432 fp16 = 36,864 B

    wpack_kernel<<<72, 256, 0, stream>>>(w, wpk);
    conv_mfma_kernel<<<64 * 127, 256, 0, stream>>>(x, (const f16x8*)wpk, bias, out);
}

// Round 4
// 100.756 us; speedup vs baseline: 7.2161x; 1.6515x over previous
//
#include <hip/hip_runtime.h>
#include <math.h>

#define CIN    16
#define COUT   64
#define H      256
#define W      256
#define OH     254
#define OW     254
#define NTAP   9
#define NSTRIP 8
#define RING   6

typedef _Float16 f16x8  __attribute__((ext_vector_type(8)));
typedef float    f32x16 __attribute__((ext_vector_type(16)));

// Bank-conflict-free slot map for both stride-2-w writes and stride-1-w reads.
#define XSLOT(w, g) ((((w) << 1) | (g)) ^ (((w) >> 2) & 7))

// weight pack: [tap 9][msub 2][lane 64][e 8] fp16; co=(l&31)+32m, cin=8*(l>>5)+e
__global__ void wpack_kernel(const float* __restrict__ w, _Float16* __restrict__ wpk) {
    int idx = blockIdx.x * 256 + threadIdx.x;   // 0..9215
    if (idx >= NTAP * 2 * 64 * 8) return;
    int e = idx & 7, l = (idx >> 3) & 63, m = (idx >> 9) & 1, t = idx >> 10;
    int co  = (l & 31) + 32 * m;
    int cin = 8 * (l >> 5) + e;
    wpk[idx] = (_Float16)w[((co * CIN + cin) * 3 + t / 3) * 3 + (t % 3)];
}

__device__ __forceinline__ float tanh_fast(float v) {
    float e = __expf(2.0f * v);
    return 1.0f - 2.0f * __builtin_amdgcn_rcpf(e + 1.0f);
}

__global__ __launch_bounds__(256, 2) void conv_mfma_kernel(
        const float* __restrict__ x, const f16x8* __restrict__ wpk,
        const float* __restrict__ bias, float* __restrict__ out) {
    __shared__ f16x8 xs[RING * 512];        // 48 KiB: 6-row ring, [w 256][g 2] swizzled
    __shared__ f16x8 wv[NTAP * 2 * 64];     // 18 KiB

    const int tid = threadIdx.x;
    int bid = blockIdx.x;
    int nb  = (bid & 7) * 64 + (bid >> 3);  // 512 blocks, %8==0 -> bijective XCD swizzle
    int b   = nb >> 3;                      // image
    int s   = nb & 7;                       // row strip
    const int npairs = (s == NSTRIP - 1) ? 15 : 16;
    const int oh0 = s * 32;

    const float* xb = x + (size_t)b * CIN * H * W;

    for (int i = tid; i < NTAP * 2 * 64; i += 256) wv[i] = wpk[i];

    const int rsel = tid >> 7;              // which of 2 rows this thread stages
    const int w2   = (tid & 127) * 2;       // staged w-pair

    // prologue: stage input rows oh0..oh0+3 into ring 0..3
    #pragma unroll
    for (int pass = 0; pass < 2; ++pass) {
        int row = oh0 + 2 * pass + rsel;
        const float* p = xb + (size_t)row * W + w2;
        float2 vv[16];
        #pragma unroll
        for (int c = 0; c < 16; ++c) vv[c] = *(const float2*)(p + (size_t)c * H * W);
        int ring = 2 * pass + rsel;
        #pragma unroll
        for (int g = 0; g < 2; ++g)
            #pragma unroll
            for (int o = 0; o < 2; ++o) {
                f16x8 q;
                #pragma unroll
                for (int e = 0; e < 8; ++e)
                    q[e] = (_Float16)(o == 0 ? vv[8 * g + e].x : vv[8 * g + e].y);
                xs[ring * 512 + XSLOT(w2 + o, g)] = q;
            }
    }
    __syncthreads();

    const int lane = tid & 63;
    const int wave = tid >> 6;
    const int ohl  = wave >> 1;             // local output row (0/1) within pair
    const int ph   = (wave & 1) * 128;      // pixel half
    const int l31  = lane & 31;
    const int g2   = lane >> 5;

    // hoisted fragment slot offsets (invariant across pairs/taps' rows)
    int off[3][4];
    #pragma unroll
    for (int kw = 0; kw < 3; ++kw)
        #pragma unroll
        for (int n = 0; n < 4; ++n) {
            int w = ph + 32 * n + l31 + kw;
            if (w > 255) w = 255;           // halo beyond 255: outputs masked anyway
            off[kw][n] = XSLOT(w, g2);
        }

    // bias per C/D layout: col=l31 (px), row=(r&3)+8*(r>>2)+4*g2+32m (co)
    float binit[2][16];
    #pragma unroll
    for (int m = 0; m < 2; ++m)
        #pragma unroll
        for (int r = 0; r < 16; ++r)
            binit[m][r] = bias[(r & 3) + 8 * (r >> 2) + 4 * g2 + 32 * m];

    f32x16 acc[2][4];
    #pragma unroll
    for (int m = 0; m < 2; ++m)
        #pragma unroll
        for (int n = 0; n < 4; ++n)
            #pragma unroll
            for (int r = 0; r < 16; ++r)
                acc[m][n][r] = binit[m][r];

    for (int p = 0; p < npairs; ++p) {
        // T14 issue-early: prefetch next 2 input rows into registers
        float2 vv[16];
        const bool pf = (p + 1 < npairs);
        if (pf) {
            int row = oh0 + 2 * p + 4 + rsel;
            const float* pp = xb + (size_t)row * W + w2;
            #pragma unroll
            for (int c = 0; c < 16; ++c) vv[c] = *(const float2*)(pp + (size_t)c * H * W);
        }

        int hb = 2 * p + ohl;
        int r0 = hb % RING, r1 = (hb + 1) % RING, r2 = (hb + 2) % RING;
        const f16x8* xr0 = xs + r0 * 512;
        const f16x8* xr1 = xs + r1 * 512;
        const f16x8* xr2 = xs + r2 * 512;

        #pragma unroll
        for (int t = 0; t < NTAP; ++t) {
            const int kh = t / 3, kw = t % 3;
            f16x8 a0 = wv[(t * 2 + 0) * 64 + lane];
            f16x8 a1 = wv[(t * 2 + 1) * 64 + lane];
            const f16x8* xr = (kh == 0) ? xr0 : (kh == 1) ? xr1 : xr2;
            #pragma unroll
            for (int n = 0; n < 4; ++n) {
                f16x8 bf = xr[off[kw][n]];
                acc[0][n] = __builtin_amdgcn_mfma_f32_32x32x16_f16(a0, bf, acc[0][n], 0, 0, 0);
                acc[1][n] = __builtin_amdgcn_mfma_f32_32x32x16_f16(a1, bf, acc[1][n], 0, 0, 0);
            }
        }

        // epilogue: min over 64 cout -> double tanh -> store; reset acc
        const int oh = oh0 + 2 * p + ohl;
        #pragma unroll
        for (int n = 0; n < 4; ++n) {
            float mn = fminf(acc[0][n][0], acc[1][n][0]);
            #pragma unroll
            for (int r = 1; r < 16; ++r)
                mn = fminf(mn, fminf(acc[0][n][r], acc[1][n][r]));
            mn = fminf(mn, __shfl_xor(mn, 32));
            float t2 = tanh_fast(tanh_fast(mn));
            int px = ph + 32 * n + l31;
            if (g2 == 0 && px < OW)
                out[((size_t)b * OH + oh) * OW + px] = t2;
            #pragma unroll
            for (int m = 0; m < 2; ++m)
                #pragma unroll
                for (int r = 0; r < 16; ++r)
                    acc[m][n][r] = binit[m][r];
        }

        // write-late: pack prefetched rows into ring slots (2p+4, 2p+5) mod 6
        if (pf) {
            int ring = (2 * p + 4 + rsel) % RING;
            #pragma unroll
            for (int g = 0; g < 2; ++g)
                #pragma unroll
                for (int o = 0; o < 2; ++o) {
                    f16x8 q;
                    #pragma unroll
                    for (int e = 0; e < 8; ++e)
                        q[e] = (_Float16)(o == 0 ? vv[8 * g + e].x : vv[8 * g + e].y);
                    xs[ring * 512 + XSLOT(w2 + o, g)] = q;
                }
        }
        __syncthreads();   // one barrier per pair: writes visible before next reads
    }
}

extern "C" void kernel_launch(void* const* d_in, const int* in_sizes, int n_in,
                              void* d_out, int out_size, void* d_ws, size_t ws_size,
                              hipStream_t stream) {
    const float* x    = (const float*)d_in[0];
    const float* w    = (const float*)d_in[1];
    const float* bias = (const float*)d_in[2];
    float* out = (float*)d_out;
    _Float16* wpk = (_Float16*)d_ws;   // 9216 fp16 = 18,432 B

    wpack_kernel<<<36, 256, 0, stream>>>(w, wpk);
    conv_mfma_kernel<<<512, 256, 0, stream>>>(x, (const f16x8*)wpk, bias, out);
}

// Round 5
// 93.435 us; speedup vs baseline: 7.7816x; 1.0784x over previous
//
#include <hip/hip_runtime.h>
#include <math.h>

#define CIN    16
#define COUT   64
#define H      256
#define W      256
#define OH     254
#define OW     254
#define NTAP   9
#define RING   10

typedef _Float16 f16x8  __attribute__((ext_vector_type(8)));
typedef float    f32x16 __attribute__((ext_vector_type(16)));

// Conflict-free slot map (verified: reads 8 lanes/bank-quad min, writes too).
#define XSLOT(w, g) ((((w) << 1) | (g)) ^ (((w) >> 2) & 7))

// weight pack: [tap 9][msub 2][lane 64][e 8] fp16; co=(l&31)+32m, cin=8*(l>>5)+e
__global__ void wpack_kernel(const float* __restrict__ w, _Float16* __restrict__ wpk) {
    int idx = blockIdx.x * 256 + threadIdx.x;   // 0..9215
    if (idx >= NTAP * 2 * 64 * 8) return;
    int e = idx & 7, l = (idx >> 3) & 63, m = (idx >> 9) & 1, t = idx >> 10;
    int co  = (l & 31) + 32 * m;
    int cin = 8 * (l >> 5) + e;
    wpk[idx] = (_Float16)w[((co * CIN + cin) * 3 + t / 3) * 3 + (t % 3)];
}

__device__ __forceinline__ float tanh_fast(float v) {
    float e = __expf(2.0f * v);
    return 1.0f - 2.0f * __builtin_amdgcn_rcpf(e + 1.0f);
}

// 512 threads = 8 waves; block = 64-row strip of one image; 1 block/CU.
// wave: ohl = wave>>2 (row in pair), ph = (wave&3)*64 (px quarter), n=0..1.
__global__ __launch_bounds__(512, 2) void conv_mfma_kernel(
        const float* __restrict__ x, const f16x8* __restrict__ wpk,
        const float* __restrict__ bias, float* __restrict__ out) {
    // 80 KiB ring (+1 KiB pad -> forces 1 block/CU so no CU gets 2 blocks)
    __shared__ f16x8 xs[RING * 512 + 64];

    const int tid = threadIdx.x;
    const int b   = blockIdx.x >> 2;            // image
    const int s   = blockIdx.x & 3;             // 64-row strip
    const int oh0 = s * 64;
    const int npairs = (s == 3) ? 31 : 32;

    const float* xb = x + (size_t)b * CIN * H * W;

    // ---- weights: global -> 72 VGPRs (pair-invariant, no LDS) ----
    const int lane = tid & 63;
    f16x8 wreg[NTAP][2];
#pragma unroll
    for (int t = 0; t < NTAP; ++t)
#pragma unroll
        for (int m = 0; m < 2; ++m)
            wreg[t][m] = wpk[(t * 2 + m) * 64 + lane];

    // ---- staging thread mapping: t = [g(1)][r(1)][pp(7)] ----
    const int gld  = tid >> 8;                  // cin group (8 cin)
    const int rld  = (tid >> 7) & 1;            // row within pair
    const int pp   = tid & 127;                 // pixel pair
    const int w2   = pp * 2;

#define STAGE(rowAbs, slot)                                                     \
    {                                                                           \
        int row_ = (rowAbs) > 255 ? 255 : (rowAbs);                             \
        const float* p_ = xb + (size_t)row_ * W + w2;                           \
        float2 vv_[8];                                                          \
        _Pragma("unroll")                                                       \
        for (int c = 0; c < 8; ++c)                                             \
            vv_[c] = *(const float2*)(p_ + (size_t)(8 * gld + c) * (H * W));    \
        f16x8 q0, q1;                                                           \
        _Pragma("unroll")                                                       \
        for (int c = 0; c < 8; ++c) { q0[c] = (_Float16)vv_[c].x;               \
                                      q1[c] = (_Float16)vv_[c].y; }             \
        xs[(slot) * 512 + XSLOT(w2,     gld)] = q0;                             \
        xs[(slot) * 512 + XSLOT(w2 + 1, gld)] = q1;                             \
    }

    // ---- prologue: rows oh0 .. oh0+5 -> ring slots 0..5 ----
#pragma unroll
    for (int i = 0; i < 3; ++i)
        STAGE(oh0 + 2 * i + rld, 2 * i + rld)
    __syncthreads();

    const int wave = tid >> 6;
    const int ohl  = wave >> 2;                 // local row in pair
    const int ph   = (wave & 3) * 64;           // pixel quarter base
    const int l31  = lane & 31;
    const int g2   = lane >> 5;

    // fragment slot offsets (pair-invariant): w = ph + 32n + l31 + kw
    int off[3][2];
#pragma unroll
    for (int kw = 0; kw < 3; ++kw)
#pragma unroll
        for (int n = 0; n < 2; ++n) {
            int w = ph + 32 * n + l31 + kw;
            if (w > 255) w = 255;
            off[kw][n] = XSLOT(w, g2);
        }

    // bias in C/D layout: col=l31 (px), row=(r&3)+8*(r>>2)+4*g2+32m (co)
    float binit[2][16];
#pragma unroll
    for (int m = 0; m < 2; ++m)
#pragma unroll
        for (int r = 0; r < 16; ++r)
            binit[m][r] = bias[(r & 3) + 8 * (r >> 2) + 4 * g2 + 32 * m];

    f32x16 acc[2][2];
#pragma unroll
    for (int m = 0; m < 2; ++m)
#pragma unroll
        for (int n = 0; n < 2; ++n)
#pragma unroll
            for (int r = 0; r < 16; ++r)
                acc[m][n][r] = binit[m][r];

    for (int p = 0; p < npairs; ++p) {
        // T14 issue-early: load rows 2p+6/7 into regs (consumed after epilogue)
        int ldrow = oh0 + 2 * p + 6 + rld;
        if (ldrow > 255) ldrow = 255;
        const float* lp = xb + (size_t)ldrow * W + w2;
        float2 vv[8];
#pragma unroll
        for (int c = 0; c < 8; ++c)
            vv[c] = *(const float2*)(lp + (size_t)(8 * gld + c) * (H * W));

        const int hb = 2 * p + ohl;
        const f16x8* xr0 = xs + (hb % RING) * 512;
        const f16x8* xr1 = xs + ((hb + 1) % RING) * 512;
        const f16x8* xr2 = xs + ((hb + 2) % RING) * 512;

#pragma unroll
        for (int t = 0; t < NTAP; ++t) {
            const int kh = t / 3, kw = t % 3;
            const f16x8* xr = (kh == 0) ? xr0 : (kh == 1) ? xr1 : xr2;
#pragma unroll
            for (int n = 0; n < 2; ++n) {
                f16x8 bf = xr[off[kw][n]];
                acc[0][n] = __builtin_amdgcn_mfma_f32_32x32x16_f16(wreg[t][0], bf, acc[0][n], 0, 0, 0);
                acc[1][n] = __builtin_amdgcn_mfma_f32_32x32x16_f16(wreg[t][1], bf, acc[1][n], 0, 0, 0);
            }
        }

        // epilogue: min over 64 cout -> tanh(tanh) -> store; reset acc
        const int oh = oh0 + 2 * p + ohl;
#pragma unroll
        for (int n = 0; n < 2; ++n) {
            float mn = fminf(acc[0][n][0], acc[1][n][0]);
#pragma unroll
            for (int r = 1; r < 16; ++r)
                mn = fminf(mn, fminf(acc[0][n][r], acc[1][n][r]));
            mn = fminf(mn, __shfl_xor(mn, 32));
            float t2 = tanh_fast(tanh_fast(mn));
            int px = ph + 32 * n + l31;
            if (g2 == 0 && px < OW)
                out[((size_t)b * OH + oh) * OW + px] = t2;
#pragma unroll
            for (int m = 0; m < 2; ++m)
#pragma unroll
                for (int r = 0; r < 16; ++r)
                    acc[m][n][r] = binit[m][r];
        }

        // write-late: prefetched rows -> ring slot (2p+6+rld)%RING
        {
            const int slot = (2 * p + 6 + rld) % RING;
            f16x8 q0, q1;
#pragma unroll
            for (int c = 0; c < 8; ++c) { q0[c] = (_Float16)vv[c].x;
                                          q1[c] = (_Float16)vv[c].y; }
            xs[slot * 512 + XSLOT(w2,     gld)] = q0;
            xs[slot * 512 + XSLOT(w2 + 1, gld)] = q1;
        }

        // ring distance >= 2 pairs both directions (RAW/WAR verified mod 10):
        // barrier only every second pair.
        if (p & 1) __syncthreads();
    }
}

extern "C" void kernel_launch(void* const* d_in, const int* in_sizes, int n_in,
                              void* d_out, int out_size, void* d_ws, size_t ws_size,
                              hipStream_t stream) {
    const float* x    = (const float*)d_in[0];
    const float* w    = (const float*)d_in[1];
    const float* bias = (const float*)d_in[2];
    float* out = (float*)d_out;
    _Float16* wpk = (_Float16*)d_ws;   // 9216 fp16 = 18,432 B

    wpack_kernel<<<36, 256, 0, stream>>>(w, wpk);
    conv_mfma_kernel<<<64 * 4, 512, 0, stream>>>(x, (const f16x8*)wpk, bias, out);
}